// Round 2
// baseline (305.700 us; speedup 1.0000x reference)
//
#include <hip/hip_runtime.h>

// Two-kernel split:
//  K1: f[n][t] = exp(-dot(w[t,n,0,:], ev[t,n,:]) * time[t&1])
//      one wave per (t,n) dot -> 51200 waves, fully coalesced float4 reads.
//      Output transposed to [n][t] in d_ws so K2's block n reads 800B contig.
//  K2: 100-step scan, one thread per (n,m) chain, depth-5 register prefetch.
//
// Layouts:
//   event_list [201,256,256]  (first 200 used)
//   a          [200,256,256,3]
//   w          [200,256,1,256]
//   u_begin    [256,256,3]
//   liner_w [256,3], liner_b [256]
//   out        [100,256,256] f32

#define NN 256
#define TT 200
#define SS 100
#define DEPTH 5

__global__ __launch_bounds__(256) void f_kernel(
    const float* __restrict__ timep,  // [2]
    const float* __restrict__ ev,     // [201,N,N]
    const float* __restrict__ w,      // [T,N,1,N]
    float* __restrict__ fs)           // [N,T] (transposed)
{
    // global wave id -> (t, n)
    const int lane = threadIdx.x & 63;
    const int gwave = blockIdx.x * 4 + (threadIdx.x >> 6);
    const int t = gwave >> 8;          // [0,200)
    const int n = gwave & 255;

    const size_t rowoff = (size_t)t * (NN * NN) + (size_t)n * NN;
    const float4* wp = (const float4*)(w + rowoff);
    const float4* ep = (const float4*)(ev + rowoff);
    float4 wv = wp[lane];
    float4 evv = ep[lane];
    float d = wv.x * evv.x;
    d = fmaf(wv.y, evv.y, d);
    d = fmaf(wv.z, evv.z, d);
    d = fmaf(wv.w, evv.w, d);
#pragma unroll
    for (int off = 1; off < 64; off <<= 1)
        d += __shfl_xor(d, off, 64);

    if (lane == 0) {
        const float tsel = (t & 1) ? timep[1] : timep[0];
        fs[n * TT + t] = __expf(-d * tsel);
    }
}

__global__ __launch_bounds__(256) void scan_kernel(
    const float* __restrict__ fs_g,   // [N,T]
    const float* __restrict__ ub,     // [N,N,3]
    const float* __restrict__ a,      // [T,N,N,3]
    const float* __restrict__ lw,     // [N,3]
    const float* __restrict__ lb,     // [N]
    float* __restrict__ out)          // [S,N,N]
{
    __shared__ float fs[TT];

    const int n = blockIdx.x;
    const int m = threadIdx.x;

    if (m < TT) fs[m] = fs_g[n * TT + m];
    __syncthreads();

    const size_t base    = (size_t)n * (NN * 3) + (size_t)m * 3;
    const size_t TSTRIDE = (size_t)NN * NN * 3;   // floats per t-slab
    const float* ap = a + base;

    float u0 = ub[base + 0];
    float u1 = ub[base + 1];
    float u2 = ub[base + 2];

    const float w0 = lw[n * 3 + 0];
    const float w1 = lw[n * 3 + 1];
    const float w2 = lw[n * 3 + 2];
    const float bb = lb[n];

    float* op = out + (size_t)n * NN + m;

    // depth-DEPTH register pipeline: buf[d] holds step s0+d's 6 a-values
    float buf[DEPTH][6];
#pragma unroll
    for (int d = 0; d < DEPTH; ++d) {
        const float* app = ap + (size_t)(2 * d) * TSTRIDE;
        buf[d][0] = app[0];
        buf[d][1] = app[1];
        buf[d][2] = app[2];
        buf[d][3] = app[TSTRIDE + 0];
        buf[d][4] = app[TSTRIDE + 1];
        buf[d][5] = app[TSTRIDE + 2];
    }

    for (int s0 = 0; s0 < SS; s0 += DEPTH) {
#pragma unroll
        for (int d = 0; d < DEPTH; ++d) {
            const int s = s0 + d;

            const float f0 = fs[2 * s];
            const float f1 = fs[2 * s + 1];

            float l0 = fmaf(buf[d][0], f0, fmaf(buf[d][3], f1, u0));
            float l1 = fmaf(buf[d][1], f0, fmaf(buf[d][4], f1, u1));
            float l2 = fmaf(buf[d][2], f0, fmaf(buf[d][5], f1, u2));

            // prefetch step s+DEPTH into the slot we just consumed
            const int sp = (s + DEPTH < SS) ? (s + DEPTH) : 0;
            const float* app = ap + (size_t)(2 * sp) * TSTRIDE;
            buf[d][0] = app[0];
            buf[d][1] = app[1];
            buf[d][2] = app[2];
            buf[d][3] = app[TSTRIDE + 0];
            buf[d][4] = app[TSTRIDE + 1];
            buf[d][5] = app[TSTRIDE + 2];

            float mx = fmaxf(l0, fmaxf(l1, l2));
            float e0 = __expf(l0 - mx);
            float e1 = __expf(l1 - mx);
            float e2 = __expf(l2 - mx);
            float inv = __builtin_amdgcn_rcpf(e0 + e1 + e2);
            u0 = e0 * inv;
            u1 = e1 * inv;
            u2 = e2 * inv;
            op[(size_t)s * (NN * NN)] = fmaf(u0, w0, fmaf(u1, w1, fmaf(u2, w2, bb)));
        }
    }
}

extern "C" void kernel_launch(void* const* d_in, const int* in_sizes, int n_in,
                              void* d_out, int out_size, void* d_ws, size_t ws_size,
                              hipStream_t stream) {
    const float* timep = (const float*)d_in[0];
    const float* ev    = (const float*)d_in[1];
    const float* ub    = (const float*)d_in[2];
    const float* a     = (const float*)d_in[3];
    const float* w     = (const float*)d_in[4];
    const float* lw    = (const float*)d_in[5];
    const float* lb    = (const float*)d_in[6];
    float* out = (float*)d_out;
    float* fs  = (float*)d_ws;        // [N,T] = 204800 B

    // K1: 51200 waves = 12800 blocks x 4 waves
    f_kernel<<<(TT * NN) / 4, 256, 0, stream>>>(timep, ev, w, fs);
    // K2: one block per n
    scan_kernel<<<NN, 256, 0, stream>>>(fs, ub, a, lw, lb, out);
}